// Round 3
// baseline (831.657 us; speedup 1.0000x reference)
//
#include <hip/hip_runtime.h>

#define DD 64
#define SCAN_T 1024

// ---------- CSR build ----------

__global__ __launch_bounds__(256)
void hist_kernel(const int* __restrict__ dst, int* __restrict__ degi, int nE)
{
    for (int e = blockIdx.x * blockDim.x + threadIdx.x; e < nE;
         e += gridDim.x * blockDim.x)
        atomicAdd(&degi[dst[e]], 1);
}

__global__ __launch_bounds__(SCAN_T)
void scan1_kernel(const int* __restrict__ degi, int* __restrict__ rs,
                  int* __restrict__ partials, int nN)
{
    __shared__ int s[SCAN_T];
    int tid = threadIdx.x;
    int gid = blockIdx.x * SCAN_T + tid;
    int v = (gid < nN) ? degi[gid] : 0;
    s[tid] = v;
    __syncthreads();
    for (int off = 1; off < SCAN_T; off <<= 1) {
        int t = (tid >= off) ? s[tid - off] : 0;
        __syncthreads();
        s[tid] += t;
        __syncthreads();
    }
    if (gid < nN) rs[gid] = s[tid] - v;   // exclusive
    if (tid == SCAN_T - 1) partials[blockIdx.x] = s[SCAN_T - 1];
}

__global__ void scan2_kernel(int* __restrict__ partials, int* __restrict__ rs,
                             int nblk, int nN)
{
    if (threadIdx.x == 0 && blockIdx.x == 0) {
        int running = 0;
        for (int b = 0; b < nblk; ++b) {
            int t = partials[b];
            partials[b] = running;
            running += t;
        }
        rs[nN] = running;   // == nE
    }
}

__global__ __launch_bounds__(SCAN_T)
void scan3_kernel(int* __restrict__ rs, const int* __restrict__ partials, int nN)
{
    int gid = blockIdx.x * SCAN_T + threadIdx.x;
    if (gid < nN) rs[gid] += partials[blockIdx.x];
}

__global__ __launch_bounds__(256)
void fill_kernel(const int* __restrict__ src, const int* __restrict__ dst,
                 const int* __restrict__ rs, int* __restrict__ cursor,
                 int* __restrict__ csr, int nE)
{
    for (int e = blockIdx.x * blockDim.x + threadIdx.x; e < nE;
         e += gridDim.x * blockDim.x) {
        int d = dst[e];
        int p = atomicAdd(&cursor[d], 1);
        csr[rs[d] + p] = src[e];
    }
}

// ---------- aggregation: mean over neighbors ----------
// Wave per node, lane = feature. Indices fetched 64-at-a-time with ONE
// coalesced lane-parallel load, broadcast via __shfl (cheap DS op) so the
// 8 gathers per group are independent -> deep VMEM pipe. Low VGPR -> high occ.
__global__ __launch_bounds__(256)
void aggregate_kernel(const float* __restrict__ xin,
                      const int* __restrict__ csr,
                      const int* __restrict__ rs,
                      float* __restrict__ aggr, int nN)
{
    int lane = threadIdx.x & 63;
    int w = threadIdx.x >> 6;
    int totWaves = gridDim.x * 4;
    for (int node = blockIdx.x * 4 + w; node < nN; node += totWaves) {
        int beg = rs[node], end = rs[node + 1];
        int deg = end - beg;
        float a0 = 0.f, a1 = 0.f, a2 = 0.f, a3 = 0.f;
        float a4 = 0.f, a5 = 0.f, a6 = 0.f, a7 = 0.f;
        for (int base = beg; base < end; base += 64) {
            int n = end - base;
            if (n > 64) n = 64;
            int myIdx = (lane < n) ? csr[base + lane] : 0;
            int j = 0;
            for (; j + 8 <= n; j += 8) {
                int s0 = __shfl(myIdx, j + 0);
                int s1 = __shfl(myIdx, j + 1);
                int s2 = __shfl(myIdx, j + 2);
                int s3 = __shfl(myIdx, j + 3);
                int s4 = __shfl(myIdx, j + 4);
                int s5 = __shfl(myIdx, j + 5);
                int s6 = __shfl(myIdx, j + 6);
                int s7 = __shfl(myIdx, j + 7);
                a0 += xin[(size_t)s0 * DD + lane];
                a1 += xin[(size_t)s1 * DD + lane];
                a2 += xin[(size_t)s2 * DD + lane];
                a3 += xin[(size_t)s3 * DD + lane];
                a4 += xin[(size_t)s4 * DD + lane];
                a5 += xin[(size_t)s5 * DD + lane];
                a6 += xin[(size_t)s6 * DD + lane];
                a7 += xin[(size_t)s7 * DD + lane];
            }
            for (; j < n; ++j) {
                int s0 = __shfl(myIdx, j);
                a0 += xin[(size_t)s0 * DD + lane];
            }
        }
        float inv = 1.0f / (float)(deg > 0 ? deg : 1);
        float acc = ((a0 + a1) + (a2 + a3)) + ((a4 + a5) + (a6 + a7));
        aggr[(size_t)node * DD + lane] = acc * inv;
    }
}

// ---------- dense: out = aggr@Wl.T + bl + x@Wr.T ----------
// Wave per node; lane owns output feature. Weight rows in VGPRs; node rows
// arrive as wave-uniform float4 broadcast loads.
__global__ __launch_bounds__(256)
void dense_kernel(const float* __restrict__ aggr,
                  const float* __restrict__ xin,
                  const float* __restrict__ Wl,
                  const float* __restrict__ bl,
                  const float* __restrict__ Wr,
                  float* __restrict__ out,
                  int nN)
{
    int lane = threadIdx.x & 63;
    int w = threadIdx.x >> 6;
    float wl[DD], wr[DD];
#pragma unroll
    for (int k = 0; k < DD; k += 4) {
        *(float4*)&wl[k] = *(const float4*)&Wl[lane * DD + k];
        *(float4*)&wr[k] = *(const float4*)&Wr[lane * DD + k];
    }
    float bias = bl[lane];
    int totWaves = gridDim.x * 4;
    for (int node = blockIdx.x * 4 + w; node < nN; node += totWaves) {
        const float* arow = aggr + (size_t)node * DD;
        const float* xrow = xin + (size_t)node * DD;
        float accL = 0.f, accR = 0.f;
#pragma unroll
        for (int k = 0; k < DD; k += 4) {
            float4 av = *(const float4*)(arow + k);
            float4 xv = *(const float4*)(xrow + k);
            accL = fmaf(av.x, wl[k + 0], accL);
            accL = fmaf(av.y, wl[k + 1], accL);
            accL = fmaf(av.z, wl[k + 2], accL);
            accL = fmaf(av.w, wl[k + 3], accL);
            accR = fmaf(xv.x, wr[k + 0], accR);
            accR = fmaf(xv.y, wr[k + 1], accR);
            accR = fmaf(xv.z, wr[k + 2], accR);
            accR = fmaf(xv.w, wr[k + 3], accR);
        }
        out[(size_t)node * DD + lane] = (accL + bias) + accR;
    }
}

extern "C" void kernel_launch(void* const* d_in, const int* in_sizes, int n_in,
                              void* d_out, int out_size, void* d_ws, size_t ws_size,
                              hipStream_t stream)
{
    const float* x   = (const float*)d_in[0];
    const int*   ei  = (const int*)d_in[1];
    const float* W1l = (const float*)d_in[2];
    const float* b1l = (const float*)d_in[3];
    const float* W1r = (const float*)d_in[4];
    const float* W2l = (const float*)d_in[5];
    const float* b2l = (const float*)d_in[6];
    const float* W2r = (const float*)d_in[7];
    float* out = (float*)d_out;

    int nN = in_sizes[0] / DD;   // 100000
    int nE = in_sizes[1] / 2;    // 1600000
    const int* src = ei;
    const int* dst = ei + nE;

    // ws layout: degi[nN] | rs[nN+1] | partials[128] | csr[nE] | pad |
    //            aggrbuf[nN*DD] | x1[nN*DD]   (~58.5 MB)
    int* degi     = (int*)d_ws;
    int* rs       = degi + nN;
    int* partials = rs + nN + 1;
    int* csr      = partials + 128;
    size_t ofs = (size_t)(nN + nN + 1 + 128 + nE);
    ofs = (ofs + 3) & ~(size_t)3;            // 16B align
    float* aggrbuf = (float*)d_ws + ofs;
    float* x1      = aggrbuf + (size_t)nN * DD;

    int nblk = (nN + SCAN_T - 1) / SCAN_T;   // 98

    // 1) degree histogram
    hipMemsetAsync(degi, 0, sizeof(int) * (size_t)nN, stream);
    hist_kernel<<<2048, 256, 0, stream>>>(dst, degi, nE);
    // 2) exclusive scan -> row_start
    scan1_kernel<<<nblk, SCAN_T, 0, stream>>>(degi, rs, partials, nN);
    scan2_kernel<<<1, 64, 0, stream>>>(partials, rs, nblk, nN);
    scan3_kernel<<<nblk, SCAN_T, 0, stream>>>(rs, partials, nN);
    // 3) fill CSR (degi reused as cursor)
    hipMemsetAsync(degi, 0, sizeof(int) * (size_t)nN, stream);
    fill_kernel<<<2048, 256, 0, stream>>>(src, dst, rs, degi, csr, nE);

    // 4) layer 1
    aggregate_kernel<<<6144, 256, 0, stream>>>(x, csr, rs, aggrbuf, nN);
    dense_kernel<<<4096, 256, 0, stream>>>(aggrbuf, x, W1l, b1l, W1r, x1, nN);
    // 5) layer 2
    aggregate_kernel<<<6144, 256, 0, stream>>>(x1, csr, rs, aggrbuf, nN);
    dense_kernel<<<4096, 256, 0, stream>>>(aggrbuf, x1, W2l, b2l, W2r, out, nN);
}

// Round 4
// 682.205 us; speedup vs baseline: 1.2191x; 1.2191x over previous
//
#include <hip/hip_runtime.h>

#define DD 64
#define SCAN_T 1024
#define TILE_N 64

// ---------- CSR build ----------

__global__ __launch_bounds__(256)
void hist_kernel(const int* __restrict__ dst, int* __restrict__ degi, int nE)
{
    for (int e = blockIdx.x * blockDim.x + threadIdx.x; e < nE;
         e += gridDim.x * blockDim.x)
        atomicAdd(&degi[dst[e]], 1);
}

__global__ __launch_bounds__(SCAN_T)
void scan1_kernel(const int* __restrict__ degi, int* __restrict__ rs,
                  int* __restrict__ partials, int nN)
{
    __shared__ int s[SCAN_T];
    int tid = threadIdx.x;
    int gid = blockIdx.x * SCAN_T + tid;
    int v = (gid < nN) ? degi[gid] : 0;
    s[tid] = v;
    __syncthreads();
    for (int off = 1; off < SCAN_T; off <<= 1) {
        int t = (tid >= off) ? s[tid - off] : 0;
        __syncthreads();
        s[tid] += t;
        __syncthreads();
    }
    if (gid < nN) rs[gid] = s[tid] - v;   // exclusive
    if (tid == SCAN_T - 1) partials[blockIdx.x] = s[SCAN_T - 1];
}

__global__ void scan2_kernel(int* __restrict__ partials, int* __restrict__ rs,
                             int nblk, int nN)
{
    if (threadIdx.x == 0 && blockIdx.x == 0) {
        int running = 0;
        for (int b = 0; b < nblk; ++b) {
            int t = partials[b];
            partials[b] = running;
            running += t;
        }
        rs[nN] = running;   // == nE
    }
}

__global__ __launch_bounds__(SCAN_T)
void scan3_kernel(int* __restrict__ rs, const int* __restrict__ partials, int nN)
{
    int gid = blockIdx.x * SCAN_T + threadIdx.x;
    if (gid < nN) rs[gid] += partials[blockIdx.x];
}

__global__ __launch_bounds__(256)
void fill_kernel(const int* __restrict__ src, const int* __restrict__ dst,
                 const int* __restrict__ rs, int* __restrict__ cursor,
                 int* __restrict__ csr, int nE)
{
    for (int e = blockIdx.x * blockDim.x + threadIdx.x; e < nE;
         e += gridDim.x * blockDim.x) {
        int d = dst[e];
        int p = atomicAdd(&cursor[d], 1);
        csr[rs[d] + p] = src[e];
    }
}

// ---------- aggregation: mean over neighbors ----------
// Wave per node, lane = feature. Indices fetched 64-at-a-time with ONE
// coalesced lane-parallel load, broadcast via __shfl so the 8 gathers per
// group are independent -> deep VMEM pipe. Low VGPR -> high occupancy.
__global__ __launch_bounds__(256)
void aggregate_kernel(const float* __restrict__ xin,
                      const int* __restrict__ csr,
                      const int* __restrict__ rs,
                      float* __restrict__ aggr, int nN)
{
    int lane = threadIdx.x & 63;
    int w = threadIdx.x >> 6;
    int totWaves = gridDim.x * 4;
    for (int node = blockIdx.x * 4 + w; node < nN; node += totWaves) {
        int beg = rs[node], end = rs[node + 1];
        int deg = end - beg;
        float a0 = 0.f, a1 = 0.f, a2 = 0.f, a3 = 0.f;
        float a4 = 0.f, a5 = 0.f, a6 = 0.f, a7 = 0.f;
        for (int base = beg; base < end; base += 64) {
            int n = end - base;
            if (n > 64) n = 64;
            int myIdx = (lane < n) ? csr[base + lane] : 0;
        int j = 0;
            for (; j + 8 <= n; j += 8) {
                int s0 = __shfl(myIdx, j + 0);
                int s1 = __shfl(myIdx, j + 1);
                int s2 = __shfl(myIdx, j + 2);
                int s3 = __shfl(myIdx, j + 3);
                int s4 = __shfl(myIdx, j + 4);
                int s5 = __shfl(myIdx, j + 5);
                int s6 = __shfl(myIdx, j + 6);
                int s7 = __shfl(myIdx, j + 7);
                a0 += xin[(size_t)s0 * DD + lane];
                a1 += xin[(size_t)s1 * DD + lane];
                a2 += xin[(size_t)s2 * DD + lane];
                a3 += xin[(size_t)s3 * DD + lane];
                a4 += xin[(size_t)s4 * DD + lane];
                a5 += xin[(size_t)s5 * DD + lane];
                a6 += xin[(size_t)s6 * DD + lane];
                a7 += xin[(size_t)s7 * DD + lane];
            }
            for (; j < n; ++j) {
                int s0 = __shfl(myIdx, j);
                a0 += xin[(size_t)s0 * DD + lane];
            }
        }
        float inv = 1.0f / (float)(deg > 0 ? deg : 1);
        float acc = ((a0 + a1) + (a2 + a3)) + ((a4 + a5) + (a6 + a7));
        aggr[(size_t)node * DD + lane] = acc * inv;
    }
}

// ---------- dense: out = aggr@Wl.T + bl + x@Wr.T ----------
// One block per 64-node tile. Stage the tile's aggr+x rows in LDS (coalesced
// strided float4 loads, conflict-free LDS writes), then each wave computes 16
// nodes via LDS *broadcast* reads (uniform addr = free) against per-lane
// weight rows held in VGPRs. Coalesced 256B output stores.
__global__ __launch_bounds__(256)
void dense_kernel(const float* __restrict__ aggr,
                  const float* __restrict__ xin,
                  const float* __restrict__ Wl,
                  const float* __restrict__ bl,
                  const float* __restrict__ Wr,
                  float* __restrict__ out,
                  int nN)
{
    __shared__ float a_lds[TILE_N * DD];
    __shared__ float x_lds[TILE_N * DD];
    int tid = threadIdx.x;
    int lane = tid & 63;
    int w = tid >> 6;

    // per-lane weight rows (row f of Wl/Wr, since out = in @ W.T)
    float wl[DD], wr[DD];
#pragma unroll
    for (int k = 0; k < DD; k += 4) {
        *(float4*)&wl[k] = *(const float4*)&Wl[lane * DD + k];
        *(float4*)&wr[k] = *(const float4*)&Wr[lane * DD + k];
    }
    float bias = bl[lane];

    int base = blockIdx.x * TILE_N;
    // stage: 4096 floats per matrix; iteration i: thread t handles float4 at
    // flat = t*4 + i*1024  (lane-consecutive float4s -> coalesced global,
    // conflict-free LDS)
#pragma unroll
    for (int i = 0; i < 4; ++i) {
        int flat = tid * 4 + i * 1024;
        int row = flat >> 6;
        int grow = base + row;
        if (grow >= nN) grow = nN - 1;          // clamp tail (harmless reads)
        int col = flat & 63;
        *(float4*)&a_lds[flat] = *(const float4*)(aggr + (size_t)grow * DD + col);
        *(float4*)&x_lds[flat] = *(const float4*)(xin  + (size_t)grow * DD + col);
    }
    __syncthreads();

    // wave w computes nodes [w*16, w*16+16) of the tile
#pragma unroll 2
    for (int i = 0; i < 16; ++i) {
        int n = w * 16 + i;
        int gn = base + n;
        if (gn >= nN) break;                    // wave-uniform
        const float* ar = &a_lds[n * DD];
        const float* xr = &x_lds[n * DD];
        float accL = 0.f, accR = 0.f;
#pragma unroll
        for (int k = 0; k < DD; k += 4) {
            float4 av = *(const float4*)(ar + k);
            float4 xv = *(const float4*)(xr + k);
            accL = fmaf(av.x, wl[k + 0], accL);
            accL = fmaf(av.y, wl[k + 1], accL);
            accL = fmaf(av.z, wl[k + 2], accL);
            accL = fmaf(av.w, wl[k + 3], accL);
            accR = fmaf(xv.x, wr[k + 0], accR);
            accR = fmaf(xv.y, wr[k + 1], accR);
            accR = fmaf(xv.z, wr[k + 2], accR);
            accR = fmaf(xv.w, wr[k + 3], accR);
        }
        out[(size_t)gn * DD + lane] = (accL + bias) + accR;
    }
}

extern "C" void kernel_launch(void* const* d_in, const int* in_sizes, int n_in,
                              void* d_out, int out_size, void* d_ws, size_t ws_size,
                              hipStream_t stream)
{
    const float* x   = (const float*)d_in[0];
    const int*   ei  = (const int*)d_in[1];
    const float* W1l = (const float*)d_in[2];
    const float* b1l = (const float*)d_in[3];
    const float* W1r = (const float*)d_in[4];
    const float* W2l = (const float*)d_in[5];
    const float* b2l = (const float*)d_in[6];
    const float* W2r = (const float*)d_in[7];
    float* out = (float*)d_out;

    int nN = in_sizes[0] / DD;   // 100000
    int nE = in_sizes[1] / 2;    // 1600000
    const int* src = ei;
    const int* dst = ei + nE;

    // ws layout: degi[nN] | rs[nN+1] | partials[128] | csr[nE] | pad |
    //            aggrbuf[nN*DD] | x1[nN*DD]
    int* degi     = (int*)d_ws;
    int* rs       = degi + nN;
    int* partials = rs + nN + 1;
    int* csr      = partials + 128;
    size_t ofs = (size_t)(nN + nN + 1 + 128 + nE);
    ofs = (ofs + 3) & ~(size_t)3;            // 16B align
    float* aggrbuf = (float*)d_ws + ofs;
    float* x1      = aggrbuf + (size_t)nN * DD;

    int nblk = (nN + SCAN_T - 1) / SCAN_T;   // 98
    int ntile = (nN + TILE_N - 1) / TILE_N;  // 1563

    // 1) degree histogram
    hipMemsetAsync(degi, 0, sizeof(int) * (size_t)nN, stream);
    hist_kernel<<<2048, 256, 0, stream>>>(dst, degi, nE);
    // 2) exclusive scan -> row_start
    scan1_kernel<<<nblk, SCAN_T, 0, stream>>>(degi, rs, partials, nN);
    scan2_kernel<<<1, 64, 0, stream>>>(partials, rs, nblk, nN);
    scan3_kernel<<<nblk, SCAN_T, 0, stream>>>(rs, partials, nN);
    // 3) fill CSR (degi reused as cursor)
    hipMemsetAsync(degi, 0, sizeof(int) * (size_t)nN, stream);
    fill_kernel<<<2048, 256, 0, stream>>>(src, dst, rs, degi, csr, nE);

    // 4) layer 1
    aggregate_kernel<<<6144, 256, 0, stream>>>(x, csr, rs, aggrbuf, nN);
    dense_kernel<<<ntile, 256, 0, stream>>>(aggrbuf, x, W1l, b1l, W1r, x1, nN);
    // 5) layer 2
    aggregate_kernel<<<6144, 256, 0, stream>>>(x1, csr, rs, aggrbuf, nN);
    dense_kernel<<<ntile, 256, 0, stream>>>(aggrbuf, x1, W2l, b2l, W2r, out, nN);
}

// Round 5
// 500.921 us; speedup vs baseline: 1.6603x; 1.3619x over previous
//
#include <hip/hip_runtime.h>

#define DD 64
#define SCAN_T 1024
#define TILE_N 64

// ---------- CSR build ----------

__global__ __launch_bounds__(256)
void hist_kernel(const int* __restrict__ dst, int* __restrict__ degi, int nE)
{
    for (int e = blockIdx.x * blockDim.x + threadIdx.x; e < nE;
         e += gridDim.x * blockDim.x)
        atomicAdd(&degi[dst[e]], 1);
}

__global__ __launch_bounds__(SCAN_T)
void scan1_kernel(const int* __restrict__ degi, int* __restrict__ rs,
                  int* __restrict__ partials, int nN)
{
    __shared__ int s[SCAN_T];
    int tid = threadIdx.x;
    int gid = blockIdx.x * SCAN_T + tid;
    int v = (gid < nN) ? degi[gid] : 0;
    s[tid] = v;
    __syncthreads();
    for (int off = 1; off < SCAN_T; off <<= 1) {
        int t = (tid >= off) ? s[tid - off] : 0;
        __syncthreads();
        s[tid] += t;
        __syncthreads();
    }
    if (gid < nN) rs[gid] = s[tid] - v;   // exclusive
    if (tid == SCAN_T - 1) partials[blockIdx.x] = s[SCAN_T - 1];
}

__global__ void scan2_kernel(int* __restrict__ partials, int* __restrict__ rs,
                             int nblk, int nN)
{
    if (threadIdx.x == 0 && blockIdx.x == 0) {
        int running = 0;
        for (int b = 0; b < nblk; ++b) {
            int t = partials[b];
            partials[b] = running;
            running += t;
        }
        rs[nN] = running;   // == nE
    }
}

__global__ __launch_bounds__(SCAN_T)
void scan3_kernel(int* __restrict__ rs, const int* __restrict__ partials, int nN)
{
    int gid = blockIdx.x * SCAN_T + threadIdx.x;
    if (gid < nN) rs[gid] += partials[blockIdx.x];
}

__global__ __launch_bounds__(256)
void fill_kernel(const int* __restrict__ src, const int* __restrict__ dst,
                 const int* __restrict__ rs, int* __restrict__ cursor,
                 int* __restrict__ csr, int nE)
{
    for (int e = blockIdx.x * blockDim.x + threadIdx.x; e < nE;
         e += gridDim.x * blockDim.x) {
        int d = dst[e];
        int p = atomicAdd(&cursor[d], 1);
        csr[rs[d] + p] = src[e];
    }
}

// ---------- aggregation: mean over neighbors ----------
__global__ __launch_bounds__(256)
void aggregate_kernel(const float* __restrict__ xin,
                      const int* __restrict__ csr,
                      const int* __restrict__ rs,
                      float* __restrict__ aggr, int nN)
{
    int lane = threadIdx.x & 63;
    int w = threadIdx.x >> 6;
    int totWaves = gridDim.x * 4;
    for (int node = blockIdx.x * 4 + w; node < nN; node += totWaves) {
        int beg = rs[node], end = rs[node + 1];
        int deg = end - beg;
        float a0 = 0.f, a1 = 0.f, a2 = 0.f, a3 = 0.f;
        float a4 = 0.f, a5 = 0.f, a6 = 0.f, a7 = 0.f;
        for (int base = beg; base < end; base += 64) {
            int n = end - base;
            if (n > 64) n = 64;
            int myIdx = (lane < n) ? csr[base + lane] : 0;
            int j = 0;
            for (; j + 8 <= n; j += 8) {
                int s0 = __shfl(myIdx, j + 0);
                int s1 = __shfl(myIdx, j + 1);
                int s2 = __shfl(myIdx, j + 2);
                int s3 = __shfl(myIdx, j + 3);
                int s4 = __shfl(myIdx, j + 4);
                int s5 = __shfl(myIdx, j + 5);
                int s6 = __shfl(myIdx, j + 6);
                int s7 = __shfl(myIdx, j + 7);
                a0 += xin[(size_t)s0 * DD + lane];
                a1 += xin[(size_t)s1 * DD + lane];
                a2 += xin[(size_t)s2 * DD + lane];
                a3 += xin[(size_t)s3 * DD + lane];
                a4 += xin[(size_t)s4 * DD + lane];
                a5 += xin[(size_t)s5 * DD + lane];
                a6 += xin[(size_t)s6 * DD + lane];
                a7 += xin[(size_t)s7 * DD + lane];
            }
            for (; j < n; ++j) {
                int s0 = __shfl(myIdx, j);
                a0 += xin[(size_t)s0 * DD + lane];
            }
        }
        float inv = 1.0f / (float)(deg > 0 ? deg : 1);
        float acc = ((a0 + a1) + (a2 + a3)) + ((a4 + a5) + (a6 + a7));
        aggr[(size_t)node * DD + lane] = acc * inv;
    }
}

// ---------- dense pass 1: out = in @ W.T + b ----------
// 64-node tile staged in LDS; each lane holds ONE 64-float weight row in
// VGPRs (~100 VGPR total -> no spill, >=4 waves/SIMD). Broadcast LDS reads
// of node rows; coalesced 256B stores.
__global__ __launch_bounds__(256)
void dense_p1(const float* __restrict__ in,
              const float* __restrict__ W,
              const float* __restrict__ b,
              float* __restrict__ out, int nN)
{
    __shared__ float t_lds[TILE_N * DD];
    int tid = threadIdx.x;
    int lane = tid & 63;
    int w = tid >> 6;

    float wreg[DD];
#pragma unroll
    for (int k = 0; k < DD; k += 4)
        *(float4*)&wreg[k] = *(const float4*)&W[lane * DD + k];
    float bias = b[lane];

    int base = blockIdx.x * TILE_N;
#pragma unroll
    for (int i = 0; i < 4; ++i) {
        int flat = tid * 4 + i * 1024;
        int grow = base + (flat >> 6);
        if (grow >= nN) grow = nN - 1;
        *(float4*)&t_lds[flat] = *(const float4*)(in + (size_t)grow * DD + (flat & 63));
    }
    __syncthreads();

#pragma unroll 1
    for (int i = 0; i < 16; ++i) {
        int n = w * 16 + i;
        int gn = base + n;
        if (gn >= nN) break;
        const float* r = &t_lds[n * DD];
        float acc0 = 0.f, acc1 = 0.f;
#pragma unroll
        for (int k = 0; k < DD; k += 8) {
            float4 v0 = *(const float4*)(r + k);
            float4 v1 = *(const float4*)(r + k + 4);
            acc0 = fmaf(v0.x, wreg[k + 0], acc0);
            acc0 = fmaf(v0.y, wreg[k + 1], acc0);
            acc0 = fmaf(v0.z, wreg[k + 2], acc0);
            acc0 = fmaf(v0.w, wreg[k + 3], acc0);
            acc1 = fmaf(v1.x, wreg[k + 4], acc1);
            acc1 = fmaf(v1.y, wreg[k + 5], acc1);
            acc1 = fmaf(v1.z, wreg[k + 6], acc1);
            acc1 = fmaf(v1.w, wreg[k + 7], acc1);
        }
        out[(size_t)gn * DD + lane] = (acc0 + acc1) + bias;
    }
}

// ---------- dense pass 2: out += in @ W.T ----------
__global__ __launch_bounds__(256)
void dense_p2(const float* __restrict__ in,
              const float* __restrict__ W,
              float* __restrict__ out, int nN)
{
    __shared__ float t_lds[TILE_N * DD];
    int tid = threadIdx.x;
    int lane = tid & 63;
    int w = tid >> 6;

    float wreg[DD];
#pragma unroll
    for (int k = 0; k < DD; k += 4)
        *(float4*)&wreg[k] = *(const float4*)&W[lane * DD + k];

    int base = blockIdx.x * TILE_N;
#pragma unroll
    for (int i = 0; i < 4; ++i) {
        int flat = tid * 4 + i * 1024;
        int grow = base + (flat >> 6);
        if (grow >= nN) grow = nN - 1;
        *(float4*)&t_lds[flat] = *(const float4*)(in + (size_t)grow * DD + (flat & 63));
    }
    __syncthreads();

#pragma unroll 1
    for (int i = 0; i < 16; ++i) {
        int n = w * 16 + i;
        int gn = base + n;
        if (gn >= nN) break;
        const float* r = &t_lds[n * DD];
        float acc0 = 0.f, acc1 = 0.f;
#pragma unroll
        for (int k = 0; k < DD; k += 8) {
            float4 v0 = *(const float4*)(r + k);
            float4 v1 = *(const float4*)(r + k + 4);
            acc0 = fmaf(v0.x, wreg[k + 0], acc0);
            acc0 = fmaf(v0.y, wreg[k + 1], acc0);
            acc0 = fmaf(v0.z, wreg[k + 2], acc0);
            acc0 = fmaf(v0.w, wreg[k + 3], acc0);
            acc1 = fmaf(v1.x, wreg[k + 4], acc1);
            acc1 = fmaf(v1.y, wreg[k + 5], acc1);
            acc1 = fmaf(v1.z, wreg[k + 6], acc1);
            acc1 = fmaf(v1.w, wreg[k + 7], acc1);
        }
        size_t o = (size_t)gn * DD + lane;
        out[o] = out[o] + (acc0 + acc1);
    }
}

extern "C" void kernel_launch(void* const* d_in, const int* in_sizes, int n_in,
                              void* d_out, int out_size, void* d_ws, size_t ws_size,
                              hipStream_t stream)
{
    const float* x   = (const float*)d_in[0];
    const int*   ei  = (const int*)d_in[1];
    const float* W1l = (const float*)d_in[2];
    const float* b1l = (const float*)d_in[3];
    const float* W1r = (const float*)d_in[4];
    const float* W2l = (const float*)d_in[5];
    const float* b2l = (const float*)d_in[6];
    const float* W2r = (const float*)d_in[7];
    float* out = (float*)d_out;

    int nN = in_sizes[0] / DD;   // 100000
    int nE = in_sizes[1] / 2;    // 1600000
    const int* src = ei;
    const int* dst = ei + nE;

    // ws layout: degi[nN] | rs[nN+1] | partials[128] | csr[nE] | pad |
    //            aggrbuf[nN*DD] | x1[nN*DD]
    int* degi     = (int*)d_ws;
    int* rs       = degi + nN;
    int* partials = rs + nN + 1;
    int* csr      = partials + 128;
    size_t ofs = (size_t)(nN + nN + 1 + 128 + nE);
    ofs = (ofs + 3) & ~(size_t)3;            // 16B align
    float* aggrbuf = (float*)d_ws + ofs;
    float* x1      = aggrbuf + (size_t)nN * DD;

    int nblk = (nN + SCAN_T - 1) / SCAN_T;   // 98
    int ntile = (nN + TILE_N - 1) / TILE_N;  // 1563

    // 1) degree histogram
    hipMemsetAsync(degi, 0, sizeof(int) * (size_t)nN, stream);
    hist_kernel<<<2048, 256, 0, stream>>>(dst, degi, nE);
    // 2) exclusive scan -> row_start
    scan1_kernel<<<nblk, SCAN_T, 0, stream>>>(degi, rs, partials, nN);
    scan2_kernel<<<1, 64, 0, stream>>>(partials, rs, nblk, nN);
    scan3_kernel<<<nblk, SCAN_T, 0, stream>>>(rs, partials, nN);
    // 3) fill CSR (degi reused as cursor)
    hipMemsetAsync(degi, 0, sizeof(int) * (size_t)nN, stream);
    fill_kernel<<<2048, 256, 0, stream>>>(src, dst, rs, degi, csr, nE);

    // 4) layer 1
    aggregate_kernel<<<6144, 256, 0, stream>>>(x, csr, rs, aggrbuf, nN);
    dense_p1<<<ntile, 256, 0, stream>>>(aggrbuf, W1l, b1l, x1, nN);
    dense_p2<<<ntile, 256, 0, stream>>>(x, W1r, x1, nN);
    // 5) layer 2
    aggregate_kernel<<<6144, 256, 0, stream>>>(x1, csr, rs, aggrbuf, nN);
    dense_p1<<<ntile, 256, 0, stream>>>(aggrbuf, W2l, b2l, out, nN);
    dense_p2<<<ntile, 256, 0, stream>>>(x1, W2r, out, nN);
}